// Round 1
// baseline (1353.530 us; speedup 1.0000x reference)
//
#include <hip/hip_runtime.h>
#include <math.h>

#define N_NODES 50000
#define E_RAW_N 800000
#define E_TOT   (E_RAW_N + N_NODES)   // 850000 (self-loops appended)
#define NGRAPH  256
#define POOL_F  448                    // 64 + 128 + 256

// ---------------- CSR build ----------------

__global__ void k_deg(const int* __restrict__ dst_raw, int* __restrict__ deg) {
    int e = blockIdx.x * blockDim.x + threadIdx.x;
    if (e >= E_TOT) return;
    int d = (e < E_RAW_N) ? dst_raw[e] : (e - E_RAW_N);
    atomicAdd(&deg[d], 1);
}

__global__ void k_scan(const int* __restrict__ deg, int* __restrict__ rowstart) {
    __shared__ int part[1024];
    const int T = 1024;
    int tid = threadIdx.x;
    int chunk = (N_NODES + T - 1) / T;           // 49
    int begin = tid * chunk;
    int end = begin + chunk; if (end > N_NODES) end = N_NODES;
    int s = 0;
    if (begin < N_NODES) for (int i = begin; i < end; ++i) s += deg[i];
    part[tid] = s;
    __syncthreads();
    for (int off = 1; off < T; off <<= 1) {
        int v = (tid >= off) ? part[tid - off] : 0;
        __syncthreads();
        part[tid] += v;
        __syncthreads();
    }
    int run = (tid == 0) ? 0 : part[tid - 1];
    if (begin < N_NODES) {
        for (int i = begin; i < end; ++i) { rowstart[i] = run; run += deg[i]; }
    }
    if (tid == T - 1) rowstart[N_NODES] = run;
}

__global__ void k_fill(const int* __restrict__ ei, const int* __restrict__ rowstart,
                       int* __restrict__ cursor, int* __restrict__ adj) {
    int e = blockIdx.x * blockDim.x + threadIdx.x;
    if (e >= E_TOT) return;
    int s, d;
    if (e < E_RAW_N) { s = ei[e]; d = ei[E_RAW_N + e]; }
    else             { s = d = e - E_RAW_N; }
    int pos = rowstart[d] + atomicAdd(&cursor[d], 1);
    adj[pos] = s;
}

// ---------------- dense GEMM h = x @ W ----------------
// 8 nodes per block, 256 threads. thread: f = tid%F, node-group = tid/F.

template<int K, int F>
__global__ void k_gemm(const float* __restrict__ x, const float* __restrict__ W,
                       float* __restrict__ h) {
    constexpr int NB  = 8;
    constexpr int TPF = 256 / F;   // node groups
    constexpr int NPT = NB / TPF;  // nodes per thread
    __shared__ float xs[NB][K];
    int n0 = blockIdx.x * NB;
    int tid = threadIdx.x;
    for (int i = tid; i < NB * K; i += 256) {
        int nn = i / K, kk = i % K;
        int gn = n0 + nn;
        xs[nn][kk] = (gn < N_NODES) ? x[(size_t)gn * K + kk] : 0.f;
    }
    __syncthreads();
    int f  = tid % F;
    int ng = tid / F;
    float acc[NPT];
#pragma unroll
    for (int j = 0; j < NPT; ++j) acc[j] = 0.f;
    for (int k = 0; k < K; ++k) {
        float wv = W[k * F + f];
#pragma unroll
        for (int j = 0; j < NPT; ++j) acc[j] += xs[ng * NPT + j][k] * wv;
    }
#pragma unroll
    for (int j = 0; j < NPT; ++j) {
        int gn = n0 + ng * NPT + j;
        if (gn < N_NODES) h[(size_t)gn * F + f] = acc[j];
    }
}

// ---------------- attention logits per node ----------------

template<int F, int C>
__global__ void k_al(const float* __restrict__ h, const float* __restrict__ a_src,
                     const float* __restrict__ a_dst,
                     float* __restrict__ al_s, float* __restrict__ al_d) {
    int idx = blockIdx.x * blockDim.x + threadIdx.x;  // n*2 + hd
    if (idx >= N_NODES * 2) return;
    int n = idx >> 1, hd = idx & 1;
    const float* hp = h + (size_t)n * F + hd * C;
    const float* as = a_src + hd * C;
    const float* ad = a_dst + hd * C;
    float ss = 0.f, sd = 0.f;
    for (int c = 0; c < C; ++c) { float v = hp[c]; ss += v * as[c]; sd += v * ad[c]; }
    al_s[idx] = ss; al_d[idx] = sd;
}

// ---------------- per-dst gather: softmax-weighted sum ----------------
// one 64-lane wave per dst node; FPL = F/64 features per lane.

template<int F, int C>
__global__ void __launch_bounds__(256) k_gather(
        const int* __restrict__ rowstart, const int* __restrict__ adj,
        const float* __restrict__ h, const float* __restrict__ al_s,
        const float* __restrict__ al_d, const float* __restrict__ bias,
        float* __restrict__ xpre) {
    constexpr int FPL = F / 64;  // 1, 2, 4
    int wave = (blockIdx.x * 256 + threadIdx.x) >> 6;
    int lane = threadIdx.x & 63;
    if (wave >= N_NODES) return;
    int n = wave;
    int rs = rowstart[n], re = rowstart[n + 1];
    float2 aldv = *reinterpret_cast<const float2*>(al_d + n * 2);
    float ald0 = aldv.x, ald1 = aldv.y;

    // pass 1: per-head max over incoming edges
    float m0 = -1e30f, m1 = -1e30f;
    for (int i = rs + lane; i < re; i += 64) {
        int s = adj[i];
        float2 asv = *reinterpret_cast<const float2*>(al_s + s * 2);
        float v0 = asv.x + ald0; v0 = v0 > 0.f ? v0 : 0.2f * v0;
        float v1 = asv.y + ald1; v1 = v1 > 0.f ? v1 : 0.2f * v1;
        m0 = fmaxf(m0, v0); m1 = fmaxf(m1, v1);
    }
#pragma unroll
    for (int o = 1; o < 64; o <<= 1) {
        m0 = fmaxf(m0, __shfl_xor(m0, o));
        m1 = fmaxf(m1, __shfl_xor(m1, o));
    }

    // pass 2: exp-sum + weighted feature accumulation
    float acc[FPL];
#pragma unroll
    for (int j = 0; j < FPL; ++j) acc[j] = 0.f;
    float se0 = 0.f, se1 = 0.f;
    for (int i = rs; i < re; ++i) {
        int s = adj[i];
        float2 asv = *reinterpret_cast<const float2*>(al_s + s * 2);
        float v0 = asv.x + ald0; v0 = v0 > 0.f ? v0 : 0.2f * v0;
        float v1 = asv.y + ald1; v1 = v1 > 0.f ? v1 : 0.2f * v1;
        float e0 = __expf(v0 - m0), e1 = __expf(v1 - m1);
        se0 += e0; se1 += e1;
        float ee = (lane < 32) ? e0 : e1;   // head = (lane*FPL)/C == lane>>5 for all layers
        const float* hp = h + (size_t)s * F + lane * FPL;
        if constexpr (FPL == 4) {
            float4 h4 = *reinterpret_cast<const float4*>(hp);
            acc[0] += ee * h4.x; acc[1] += ee * h4.y;
            acc[2] += ee * h4.z; acc[3] += ee * h4.w;
        } else if constexpr (FPL == 2) {
            float2 h2 = *reinterpret_cast<const float2*>(hp);
            acc[0] += ee * h2.x; acc[1] += ee * h2.y;
        } else {
            acc[0] += ee * hp[0];
        }
    }
    float se = (lane < 32) ? se0 : se1;
    float inv = 1.f / (se + 1e-16f);
#pragma unroll
    for (int j = 0; j < FPL; ++j) {
        int f = lane * FPL + j;
        xpre[(size_t)n * F + f] = acc[j] * inv + bias[f];
    }
}

// ---------------- BatchNorm stats ----------------

template<int F>
__global__ void k_bnstats(const float* __restrict__ x, float* __restrict__ bnsum,
                          float* __restrict__ bnsumsq) {
    int tid = blockIdx.x * blockDim.x + threadIdx.x;
    const int T = 256 * 256;
    int f = tid % F;
    int nstride = T / F;
    float s = 0.f, sq = 0.f;
    for (int n = tid / F; n < N_NODES; n += nstride) {
        float v = x[(size_t)n * F + f];
        s += v; sq += v * v;
    }
    atomicAdd(&bnsum[f], s);
    atomicAdd(&bnsumsq[f], sq);
}

// ---------------- BN apply + leaky-relu + pooling ----------------

template<int F>
__global__ void k_bnapply(const float* __restrict__ x, const float* __restrict__ bnsum,
                          const float* __restrict__ bnsumsq, const float* __restrict__ g,
                          const float* __restrict__ be, const int* __restrict__ batch,
                          float* __restrict__ xnext, float* __restrict__ p, int poff) {
    int idx = blockIdx.x * blockDim.x + threadIdx.x;
    if (idx >= N_NODES * F) return;
    int n = idx / F, f = idx % F;
    const float invN = 1.f / (float)N_NODES;
    float mean = bnsum[f] * invN;
    float var  = bnsumsq[f] * invN - mean * mean;
    float y = (x[idx] - mean) * rsqrtf(var + 1e-5f) * g[f] + be[f];
    y = y > 0.f ? y : 0.01f * y;
    xnext[idx] = y;
    atomicAdd(&p[batch[n] * POOL_F + poff + f], y);
}

// ---------------- final MLP ----------------

__global__ void k_mlp(const float* __restrict__ p, const float* __restrict__ Wc1,
                      const float* __restrict__ bc1, const float* __restrict__ Wc2,
                      const float* __restrict__ bc2, const float* __restrict__ Wc3,
                      const float* __restrict__ bc3, float* __restrict__ out) {
    __shared__ float pr[POOL_F];
    __shared__ float h1[128];
    __shared__ float h2[64];
    int g = blockIdx.x, tid = threadIdx.x;
    for (int i = tid; i < POOL_F; i += 128) pr[i] = p[g * POOL_F + i];
    __syncthreads();
    float a = bc1[tid];
    for (int k = 0; k < POOL_F; ++k) a += pr[k] * Wc1[k * 128 + tid];
    a = a > 0.f ? a : 0.01f * a;
    h1[tid] = a;
    __syncthreads();
    if (tid < 64) {
        float b = bc2[tid];
        for (int k = 0; k < 128; ++k) b += h1[k] * Wc2[k * 64 + tid];
        b = b > 0.f ? b : 0.01f * b;
        h2[tid] = b;
    }
    __syncthreads();
    if (tid < 2) {
        float c = bc3[tid];
        for (int k = 0; k < 64; ++k) c += h2[k] * Wc3[k * 2 + tid];
        out[g * 2 + tid] = c;
    }
}

// ---------------- launch ----------------

extern "C" void kernel_launch(void* const* d_in, const int* in_sizes, int n_in,
                              void* d_out, int out_size, void* d_ws, size_t ws_size,
                              hipStream_t stream) {
    const float* x    = (const float*)d_in[0];
    const int*   ei   = (const int*)d_in[1];
    const int*   batch= (const int*)d_in[3];
    const float* W1  = (const float*)d_in[4];
    const float* as1 = (const float*)d_in[5];
    const float* ad1 = (const float*)d_in[6];
    const float* b1  = (const float*)d_in[7];
    const float* g1  = (const float*)d_in[8];
    const float* be1 = (const float*)d_in[9];
    const float* W2  = (const float*)d_in[10];
    const float* as2 = (const float*)d_in[11];
    const float* ad2 = (const float*)d_in[12];
    const float* b2  = (const float*)d_in[13];
    const float* g2  = (const float*)d_in[14];
    const float* be2 = (const float*)d_in[15];
    const float* W3  = (const float*)d_in[16];
    const float* as3 = (const float*)d_in[17];
    const float* ad3 = (const float*)d_in[18];
    const float* b3  = (const float*)d_in[19];
    const float* g3  = (const float*)d_in[20];
    const float* be3 = (const float*)d_in[21];
    const float* Wc1 = (const float*)d_in[22];
    const float* bc1 = (const float*)d_in[23];
    const float* Wc2 = (const float*)d_in[24];
    const float* bc2 = (const float*)d_in[25];
    const float* Wc3 = (const float*)d_in[26];
    const float* bc3 = (const float*)d_in[27];
    float* out = (float*)d_out;

    char* wsb = (char*)d_ws;
    size_t off = 0;
    auto alloc = [&](size_t b) -> void* {
        void* pp = wsb + off;
        off += (b + 255) & ~(size_t)255;
        return pp;
    };
    int*   adj      = (int*)alloc((size_t)E_TOT * 4);
    int*   rowstart = (int*)alloc((size_t)(N_NODES + 1) * 4);
    int*   deg      = (int*)alloc((size_t)N_NODES * 4);
    int*   cursor   = (int*)alloc((size_t)N_NODES * 4);
    float* al_s     = (float*)alloc((size_t)N_NODES * 2 * 4);
    float* al_d     = (float*)alloc((size_t)N_NODES * 2 * 4);
    float* bn       = (float*)alloc(512 * 4);
    float* p        = (float*)alloc((size_t)NGRAPH * POOL_F * 4);
    float* bufA     = (float*)alloc((size_t)N_NODES * 256 * 4);
    float* bufB     = (float*)alloc((size_t)N_NODES * 256 * 4);
    float* bufC     = (float*)alloc((size_t)N_NODES * 256 * 4);

    hipMemsetAsync(deg, 0, (size_t)N_NODES * 4, stream);
    hipMemsetAsync(cursor, 0, (size_t)N_NODES * 4, stream);
    hipMemsetAsync(p, 0, (size_t)NGRAPH * POOL_F * 4, stream);

    int eb = (E_TOT + 255) / 256;
    k_deg<<<eb, 256, 0, stream>>>(ei + E_RAW_N, deg);
    k_scan<<<1, 1024, 0, stream>>>(deg, rowstart);
    k_fill<<<eb, 256, 0, stream>>>(ei, rowstart, cursor, adj);

    int gb = (N_NODES + 7) / 8;          // gemm blocks
    int ab = (N_NODES * 2 + 255) / 256;  // al blocks
    int wb = (N_NODES + 3) / 4;          // gather blocks (4 waves each)

    // ---- layer 1: K=128, F=64, C=32 ----
    k_gemm<128, 64><<<gb, 256, 0, stream>>>(x, W1, bufA);
    k_al<64, 32><<<ab, 256, 0, stream>>>(bufA, as1, ad1, al_s, al_d);
    k_gather<64, 32><<<wb, 256, 0, stream>>>(rowstart, adj, bufA, al_s, al_d, b1, bufB);
    hipMemsetAsync(bn, 0, 512 * 4, stream);
    k_bnstats<64><<<256, 256, 0, stream>>>(bufB, bn, bn + 256);
    k_bnapply<64><<<(N_NODES * 64 + 255) / 256, 256, 0, stream>>>(bufB, bn, bn + 256, g1, be1, batch, bufC, p, 0);

    // ---- layer 2: K=64, F=128, C=64 ----
    k_gemm<64, 128><<<gb, 256, 0, stream>>>(bufC, W2, bufA);
    k_al<128, 64><<<ab, 256, 0, stream>>>(bufA, as2, ad2, al_s, al_d);
    k_gather<128, 64><<<wb, 256, 0, stream>>>(rowstart, adj, bufA, al_s, al_d, b2, bufB);
    hipMemsetAsync(bn, 0, 512 * 4, stream);
    k_bnstats<128><<<256, 256, 0, stream>>>(bufB, bn, bn + 256);
    k_bnapply<128><<<(N_NODES * 128 + 255) / 256, 256, 0, stream>>>(bufB, bn, bn + 256, g2, be2, batch, bufC, p, 64);

    // ---- layer 3: K=128, F=256, C=128 ----
    k_gemm<128, 256><<<gb, 256, 0, stream>>>(bufC, W3, bufA);
    k_al<256, 128><<<ab, 256, 0, stream>>>(bufA, as3, ad3, al_s, al_d);
    k_gather<256, 128><<<wb, 256, 0, stream>>>(rowstart, adj, bufA, al_s, al_d, b3, bufB);
    hipMemsetAsync(bn, 0, 512 * 4, stream);
    k_bnstats<256><<<256, 256, 0, stream>>>(bufB, bn, bn + 256);
    k_bnapply<256><<<(N_NODES * 256 + 255) / 256, 256, 0, stream>>>(bufB, bn, bn + 256, g3, be3, batch, bufC, p, 192);

    // ---- readout MLP ----
    k_mlp<<<NGRAPH, 128, 0, stream>>>(p, Wc1, bc1, Wc2, bc2, Wc3, bc3, out);
}

// Round 2
// 855.480 us; speedup vs baseline: 1.5822x; 1.5822x over previous
//
#include <hip/hip_runtime.h>
#include <math.h>

#define N_NODES 50000
#define E_RAW_N 800000
#define E_TOT   (E_RAW_N + N_NODES)   // 850000 (self-loops appended)
#define NGRAPH  256
#define POOL_F  448                    // 64 + 128 + 256

// ---------------- CSR build ----------------

__global__ void k_deg(const int* __restrict__ dst_raw, int* __restrict__ deg) {
    int e = blockIdx.x * blockDim.x + threadIdx.x;
    if (e >= E_TOT) return;
    int d = (e < E_RAW_N) ? dst_raw[e] : (e - E_RAW_N);
    atomicAdd(&deg[d], 1);
}

__global__ void k_scan(const int* __restrict__ deg, int* __restrict__ rowstart) {
    __shared__ int part[1024];
    const int T = 1024;
    int tid = threadIdx.x;
    int chunk = (N_NODES + T - 1) / T;           // 49
    int begin = tid * chunk;
    int end = begin + chunk; if (end > N_NODES) end = N_NODES;
    int s = 0;
    if (begin < N_NODES) for (int i = begin; i < end; ++i) s += deg[i];
    part[tid] = s;
    __syncthreads();
    for (int off = 1; off < T; off <<= 1) {
        int v = (tid >= off) ? part[tid - off] : 0;
        __syncthreads();
        part[tid] += v;
        __syncthreads();
    }
    int run = (tid == 0) ? 0 : part[tid - 1];
    if (begin < N_NODES) {
        for (int i = begin; i < end; ++i) { rowstart[i] = run; run += deg[i]; }
    }
    if (tid == T - 1) rowstart[N_NODES] = run;
}

__global__ void k_fill(const int* __restrict__ ei, const int* __restrict__ rowstart,
                       int* __restrict__ cursor, int* __restrict__ adj) {
    int e = blockIdx.x * blockDim.x + threadIdx.x;
    if (e >= E_TOT) return;
    int s, d;
    if (e < E_RAW_N) { s = ei[e]; d = ei[E_RAW_N + e]; }
    else             { s = d = e - E_RAW_N; }
    int pos = rowstart[d] + atomicAdd(&cursor[d], 1);
    adj[pos] = s;
}

// ---------------- tiled dense GEMM h = x @ W ----------------
// BM=64 nodes x BN features per 256-thread block; BK=32; 4xTN register tile.

template<int K, int F, int BN>
__global__ void __launch_bounds__(256) k_gemm2(const float* __restrict__ x,
        const float* __restrict__ W, float* __restrict__ h) {
    constexpr int BM = 64, BK = 32;
    constexpr int TM = 4;
    constexpr int TN = BN / 16;        // 64->4, 128->8
    __shared__ float xs[BK][BM + 1];   // transposed, padded
    __shared__ float ws[BK][BN];
    int bn0 = blockIdx.y * BN;
    int n0 = blockIdx.x * BM;
    int tid = threadIdx.x;
    int tx = tid % 16;                 // f dim
    int ty = tid / 16;                 // n dim
    float acc[TM][TN];
#pragma unroll
    for (int i = 0; i < TM; ++i)
#pragma unroll
        for (int j = 0; j < TN; ++j) acc[i][j] = 0.f;

    for (int k0 = 0; k0 < K; k0 += BK) {
        // x tile: BM x BK, stored transposed
        for (int i = tid; i < BM * (BK / 4); i += 256) {
            int m = i / (BK / 4);
            int kq = i % (BK / 4);
            int gn = n0 + m;
            float4 v = (gn < N_NODES)
                ? *reinterpret_cast<const float4*>(x + (size_t)gn * K + k0 + kq * 4)
                : make_float4(0.f, 0.f, 0.f, 0.f);
            xs[kq * 4 + 0][m] = v.x; xs[kq * 4 + 1][m] = v.y;
            xs[kq * 4 + 2][m] = v.z; xs[kq * 4 + 3][m] = v.w;
        }
        // W tile: BK x BN
        for (int i = tid; i < BK * (BN / 4); i += 256) {
            int kk = i / (BN / 4);
            int fq = i % (BN / 4);
            *reinterpret_cast<float4*>(&ws[kk][fq * 4]) =
                *reinterpret_cast<const float4*>(W + (size_t)(k0 + kk) * F + bn0 + fq * 4);
        }
        __syncthreads();
#pragma unroll 4
        for (int kk = 0; kk < BK; ++kk) {
            float a[TM], b[TN];
#pragma unroll
            for (int i = 0; i < TM; ++i) a[i] = xs[kk][ty * TM + i];
#pragma unroll
            for (int j = 0; j < TN; ++j) b[j] = ws[kk][tx * TN + j];
#pragma unroll
            for (int i = 0; i < TM; ++i)
#pragma unroll
                for (int j = 0; j < TN; ++j) acc[i][j] += a[i] * b[j];
        }
        __syncthreads();
    }
#pragma unroll
    for (int i = 0; i < TM; ++i) {
        int gn = n0 + ty * TM + i;
        if (gn >= N_NODES) break;
        float* hp = h + (size_t)gn * F + bn0 + tx * TN;
        *reinterpret_cast<float4*>(hp) = make_float4(acc[i][0], acc[i][1], acc[i][2], acc[i][3]);
        if constexpr (TN == 8) {
            *reinterpret_cast<float4*>(hp + 4) = make_float4(acc[i][4], acc[i][5], acc[i][6], acc[i][7]);
        }
    }
}

// ---------------- attention logits per node ----------------

template<int F, int C>
__global__ void k_al(const float* __restrict__ h, const float* __restrict__ a_src,
                     const float* __restrict__ a_dst,
                     float* __restrict__ al_s, float* __restrict__ al_d) {
    int idx = blockIdx.x * blockDim.x + threadIdx.x;  // n*2 + hd
    if (idx >= N_NODES * 2) return;
    int n = idx >> 1, hd = idx & 1;
    const float* hp = h + (size_t)n * F + hd * C;
    const float* as = a_src + hd * C;
    const float* ad = a_dst + hd * C;
    float ss = 0.f, sd = 0.f;
    for (int c = 0; c < C; ++c) { float v = hp[c]; ss += v * as[c]; sd += v * ad[c]; }
    al_s[idx] = ss; al_d[idx] = sd;
}

// ---------------- per-dst gather: softmax-weighted sum ----------------

template<int F, int C>
__global__ void __launch_bounds__(256) k_gather(
        const int* __restrict__ rowstart, const int* __restrict__ adj,
        const float* __restrict__ h, const float* __restrict__ al_s,
        const float* __restrict__ al_d, const float* __restrict__ bias,
        float* __restrict__ xpre) {
    constexpr int FPL = F / 64;  // 1, 2, 4
    int wave = (blockIdx.x * 256 + threadIdx.x) >> 6;
    int lane = threadIdx.x & 63;
    if (wave >= N_NODES) return;
    int n = wave;
    int rs = rowstart[n], re = rowstart[n + 1];
    float2 aldv = *reinterpret_cast<const float2*>(al_d + n * 2);
    float ald0 = aldv.x, ald1 = aldv.y;

    // pass 1: per-head max over incoming edges
    float m0 = -1e30f, m1 = -1e30f;
    for (int i = rs + lane; i < re; i += 64) {
        int s = adj[i];
        float2 asv = *reinterpret_cast<const float2*>(al_s + s * 2);
        float v0 = asv.x + ald0; v0 = v0 > 0.f ? v0 : 0.2f * v0;
        float v1 = asv.y + ald1; v1 = v1 > 0.f ? v1 : 0.2f * v1;
        m0 = fmaxf(m0, v0); m1 = fmaxf(m1, v1);
    }
#pragma unroll
    for (int o = 1; o < 64; o <<= 1) {
        m0 = fmaxf(m0, __shfl_xor(m0, o));
        m1 = fmaxf(m1, __shfl_xor(m1, o));
    }

    // pass 2: exp-sum + weighted feature accumulation
    float acc[FPL];
#pragma unroll
    for (int j = 0; j < FPL; ++j) acc[j] = 0.f;
    float se0 = 0.f, se1 = 0.f;
    for (int i = rs; i < re; ++i) {
        int s = adj[i];
        float2 asv = *reinterpret_cast<const float2*>(al_s + s * 2);
        float v0 = asv.x + ald0; v0 = v0 > 0.f ? v0 : 0.2f * v0;
        float v1 = asv.y + ald1; v1 = v1 > 0.f ? v1 : 0.2f * v1;
        float e0 = __expf(v0 - m0), e1 = __expf(v1 - m1);
        se0 += e0; se1 += e1;
        float ee = (lane < 32) ? e0 : e1;   // head = lane>>5 for all layers
        const float* hp = h + (size_t)s * F + lane * FPL;
        if constexpr (FPL == 4) {
            float4 h4 = *reinterpret_cast<const float4*>(hp);
            acc[0] += ee * h4.x; acc[1] += ee * h4.y;
            acc[2] += ee * h4.z; acc[3] += ee * h4.w;
        } else if constexpr (FPL == 2) {
            float2 h2 = *reinterpret_cast<const float2*>(hp);
            acc[0] += ee * h2.x; acc[1] += ee * h2.y;
        } else {
            acc[0] += ee * hp[0];
        }
    }
    float se = (lane < 32) ? se0 : se1;
    float inv = 1.f / (se + 1e-16f);
#pragma unroll
    for (int j = 0; j < FPL; ++j) {
        int f = lane * FPL + j;
        xpre[(size_t)n * F + f] = acc[j] * inv + bias[f];
    }
}

// ---------------- BatchNorm stats ----------------

template<int F>
__global__ void k_bnstats(const float* __restrict__ x, float* __restrict__ bnsum,
                          float* __restrict__ bnsumsq) {
    int tid = blockIdx.x * blockDim.x + threadIdx.x;
    const int T = 256 * 256;
    int f = tid % F;
    int nstride = T / F;
    float s = 0.f, sq = 0.f;
    for (int n = tid / F; n < N_NODES; n += nstride) {
        float v = x[(size_t)n * F + f];
        s += v; sq += v * v;
    }
    atomicAdd(&bnsum[f], s);
    atomicAdd(&bnsumsq[f], sq);
}

// ---------------- BN apply + leaky-relu + pooling (sorted-batch run flush) ----

template<int F>
__global__ void k_bnapply2(const float* __restrict__ x, const float* __restrict__ bnsum,
                           const float* __restrict__ bnsumsq, const float* __restrict__ g,
                           const float* __restrict__ be, const int* __restrict__ batch,
                           float* __restrict__ xnext, float* __restrict__ p, int poff) {
    constexpr int NGRP = 256 / F;
    constexpr int NPB = 128;              // nodes per block
    int f = threadIdx.x % F;
    int grp = threadIdx.x / F;
    int n0 = blockIdx.x * NPB;
    int nend = n0 + NPB; if (nend > N_NODES) nend = N_NODES;
    const float invN = 1.f / (float)N_NODES;
    float mean = bnsum[f] * invN;
    float var  = bnsumsq[f] * invN - mean * mean;
    float sc = rsqrtf(var + 1e-5f) * g[f];
    float bb = be[f] - mean * sc;
    int n = n0 + grp;
    if (n >= nend) return;
    float ps = 0.f;
    int cg = batch[n];
    for (; n < nend; n += NGRP) {
        float y = x[(size_t)n * F + f] * sc + bb;
        y = y > 0.f ? y : 0.01f * y;
        xnext[(size_t)n * F + f] = y;
        int bg = batch[n];
        if (bg != cg) { atomicAdd(&p[cg * POOL_F + poff + f], ps); ps = 0.f; cg = bg; }
        ps += y;
    }
    atomicAdd(&p[cg * POOL_F + poff + f], ps);
}

// ---------------- final MLP ----------------

__global__ void k_mlp(const float* __restrict__ p, const float* __restrict__ Wc1,
                      const float* __restrict__ bc1, const float* __restrict__ Wc2,
                      const float* __restrict__ bc2, const float* __restrict__ Wc3,
                      const float* __restrict__ bc3, float* __restrict__ out) {
    __shared__ float pr[POOL_F];
    __shared__ float h1[128];
    __shared__ float h2[64];
    int g = blockIdx.x, tid = threadIdx.x;
    for (int i = tid; i < POOL_F; i += 128) pr[i] = p[g * POOL_F + i];
    __syncthreads();
    float a = bc1[tid];
    for (int k = 0; k < POOL_F; ++k) a += pr[k] * Wc1[k * 128 + tid];
    a = a > 0.f ? a : 0.01f * a;
    h1[tid] = a;
    __syncthreads();
    if (tid < 64) {
        float b = bc2[tid];
        for (int k = 0; k < 128; ++k) b += h1[k] * Wc2[k * 64 + tid];
        b = b > 0.f ? b : 0.01f * b;
        h2[tid] = b;
    }
    __syncthreads();
    if (tid < 2) {
        float c = bc3[tid];
        for (int k = 0; k < 64; ++k) c += h2[k] * Wc3[k * 2 + tid];
        out[g * 2 + tid] = c;
    }
}

// ---------------- launch ----------------

extern "C" void kernel_launch(void* const* d_in, const int* in_sizes, int n_in,
                              void* d_out, int out_size, void* d_ws, size_t ws_size,
                              hipStream_t stream) {
    const float* x    = (const float*)d_in[0];
    const int*   ei   = (const int*)d_in[1];
    const int*   batch= (const int*)d_in[3];
    const float* W1  = (const float*)d_in[4];
    const float* as1 = (const float*)d_in[5];
    const float* ad1 = (const float*)d_in[6];
    const float* b1  = (const float*)d_in[7];
    const float* g1  = (const float*)d_in[8];
    const float* be1 = (const float*)d_in[9];
    const float* W2  = (const float*)d_in[10];
    const float* as2 = (const float*)d_in[11];
    const float* ad2 = (const float*)d_in[12];
    const float* b2  = (const float*)d_in[13];
    const float* g2  = (const float*)d_in[14];
    const float* be2 = (const float*)d_in[15];
    const float* W3  = (const float*)d_in[16];
    const float* as3 = (const float*)d_in[17];
    const float* ad3 = (const float*)d_in[18];
    const float* b3  = (const float*)d_in[19];
    const float* g3  = (const float*)d_in[20];
    const float* be3 = (const float*)d_in[21];
    const float* Wc1 = (const float*)d_in[22];
    const float* bc1 = (const float*)d_in[23];
    const float* Wc2 = (const float*)d_in[24];
    const float* bc2 = (const float*)d_in[25];
    const float* Wc3 = (const float*)d_in[26];
    const float* bc3 = (const float*)d_in[27];
    float* out = (float*)d_out;

    char* wsb = (char*)d_ws;
    size_t off = 0;
    auto alloc = [&](size_t b) -> void* {
        void* pp = wsb + off;
        off += (b + 255) & ~(size_t)255;
        return pp;
    };
    int*   adj      = (int*)alloc((size_t)E_TOT * 4);
    int*   rowstart = (int*)alloc((size_t)(N_NODES + 1) * 4);
    int*   deg      = (int*)alloc((size_t)N_NODES * 4);
    int*   cursor   = (int*)alloc((size_t)N_NODES * 4);
    float* al_s     = (float*)alloc((size_t)N_NODES * 2 * 4);
    float* al_d     = (float*)alloc((size_t)N_NODES * 2 * 4);
    float* bn       = (float*)alloc(512 * 4);
    float* p        = (float*)alloc((size_t)NGRAPH * POOL_F * 4);
    float* bufA     = (float*)alloc((size_t)N_NODES * 256 * 4);
    float* bufB     = (float*)alloc((size_t)N_NODES * 256 * 4);
    float* bufC     = (float*)alloc((size_t)N_NODES * 256 * 4);

    hipMemsetAsync(deg, 0, (size_t)N_NODES * 4, stream);
    hipMemsetAsync(cursor, 0, (size_t)N_NODES * 4, stream);
    hipMemsetAsync(p, 0, (size_t)NGRAPH * POOL_F * 4, stream);

    int eb = (E_TOT + 255) / 256;
    k_deg<<<eb, 256, 0, stream>>>(ei + E_RAW_N, deg);
    k_scan<<<1, 1024, 0, stream>>>(deg, rowstart);
    k_fill<<<eb, 256, 0, stream>>>(ei, rowstart, cursor, adj);

    int gb = (N_NODES + 63) / 64;        // gemm blocks (x dim)
    int ab = (N_NODES * 2 + 255) / 256;  // al blocks
    int wb = (N_NODES + 3) / 4;          // gather blocks (4 waves each)
    int bb = (N_NODES + 127) / 128;      // bnapply blocks

    // ---- layer 1: K=128, F=64, C=32 ----
    k_gemm2<128, 64, 64><<<dim3(gb, 1), 256, 0, stream>>>(x, W1, bufA);
    k_al<64, 32><<<ab, 256, 0, stream>>>(bufA, as1, ad1, al_s, al_d);
    k_gather<64, 32><<<wb, 256, 0, stream>>>(rowstart, adj, bufA, al_s, al_d, b1, bufB);
    hipMemsetAsync(bn, 0, 512 * 4, stream);
    k_bnstats<64><<<256, 256, 0, stream>>>(bufB, bn, bn + 256);
    k_bnapply2<64><<<bb, 256, 0, stream>>>(bufB, bn, bn + 256, g1, be1, batch, bufC, p, 0);

    // ---- layer 2: K=64, F=128, C=64 ----
    k_gemm2<64, 128, 128><<<dim3(gb, 1), 256, 0, stream>>>(bufC, W2, bufA);
    k_al<128, 64><<<ab, 256, 0, stream>>>(bufA, as2, ad2, al_s, al_d);
    k_gather<128, 64><<<wb, 256, 0, stream>>>(rowstart, adj, bufA, al_s, al_d, b2, bufB);
    hipMemsetAsync(bn, 0, 512 * 4, stream);
    k_bnstats<128><<<256, 256, 0, stream>>>(bufB, bn, bn + 256);
    k_bnapply2<128><<<bb, 256, 0, stream>>>(bufB, bn, bn + 256, g2, be2, batch, bufC, p, 64);

    // ---- layer 3: K=128, F=256, C=128 ----
    k_gemm2<128, 256, 128><<<dim3(gb, 2), 256, 0, stream>>>(bufC, W3, bufA);
    k_al<256, 128><<<ab, 256, 0, stream>>>(bufA, as3, ad3, al_s, al_d);
    k_gather<256, 128><<<wb, 256, 0, stream>>>(rowstart, adj, bufA, al_s, al_d, b3, bufB);
    hipMemsetAsync(bn, 0, 512 * 4, stream);
    k_bnstats<256><<<256, 256, 0, stream>>>(bufB, bn, bn + 256);
    k_bnapply2<256><<<bb, 256, 0, stream>>>(bufB, bn, bn + 256, g3, be3, batch, bufC, p, 192);

    // ---- readout MLP ----
    k_mlp<<<NGRAPH, 128, 0, stream>>>(p, Wc1, bc1, Wc2, bc2, Wc3, bc3, out);
}

// Round 3
// 686.587 us; speedup vs baseline: 1.9714x; 1.2460x over previous
//
#include <hip/hip_runtime.h>
#include <hip/hip_fp16.h>
#include <math.h>

#define N_NODES 50000
#define E_RAW_N 800000
#define E_TOT   (E_RAW_N + N_NODES)   // 850000 (self-loops appended)
#define NGRAPH  256
#define POOL_F  448                    // 64 + 128 + 256

// ---------------- CSR build ----------------

__global__ void k_deg(const int* __restrict__ dst_raw, int* __restrict__ deg) {
    int e = blockIdx.x * blockDim.x + threadIdx.x;
    if (e >= E_TOT) return;
    int d = (e < E_RAW_N) ? dst_raw[e] : (e - E_RAW_N);
    atomicAdd(&deg[d], 1);
}

__global__ void k_scan(const int* __restrict__ deg, int* __restrict__ rowstart) {
    __shared__ int part[1024];
    const int T = 1024;
    int tid = threadIdx.x;
    int chunk = (N_NODES + T - 1) / T;           // 49
    int begin = tid * chunk;
    int end = begin + chunk; if (end > N_NODES) end = N_NODES;
    int s = 0;
    if (begin < N_NODES) for (int i = begin; i < end; ++i) s += deg[i];
    part[tid] = s;
    __syncthreads();
    for (int off = 1; off < T; off <<= 1) {
        int v = (tid >= off) ? part[tid - off] : 0;
        __syncthreads();
        part[tid] += v;
        __syncthreads();
    }
    int run = (tid == 0) ? 0 : part[tid - 1];
    if (begin < N_NODES) {
        for (int i = begin; i < end; ++i) { rowstart[i] = run; run += deg[i]; }
    }
    if (tid == T - 1) rowstart[N_NODES] = run;
}

__global__ void k_fill(const int* __restrict__ ei, const int* __restrict__ rowstart,
                       int* __restrict__ cursor, int* __restrict__ adj) {
    int e = blockIdx.x * blockDim.x + threadIdx.x;
    if (e >= E_TOT) return;
    int s, d;
    if (e < E_RAW_N) { s = ei[e]; d = ei[E_RAW_N + e]; }
    else             { s = d = e - E_RAW_N; }
    int pos = rowstart[d] + atomicAdd(&cursor[d], 1);
    adj[pos] = s;
}

// ---------------- tiled dense GEMM h = x @ W (fp16 output) ----------------

template<int K, int F, int BN>
__global__ void __launch_bounds__(256) k_gemm2(const float* __restrict__ x,
        const float* __restrict__ W, __half* __restrict__ h) {
    constexpr int BM = 64, BK = 32;
    constexpr int TM = 4;
    constexpr int TN = BN / 16;        // 64->4, 128->8
    __shared__ float xs[BK][BM + 1];   // transposed, padded
    __shared__ float ws[BK][BN];
    int bn0 = blockIdx.y * BN;
    int n0 = blockIdx.x * BM;
    int tid = threadIdx.x;
    int tx = tid % 16;                 // f dim
    int ty = tid / 16;                 // n dim
    float acc[TM][TN];
#pragma unroll
    for (int i = 0; i < TM; ++i)
#pragma unroll
        for (int j = 0; j < TN; ++j) acc[i][j] = 0.f;

    for (int k0 = 0; k0 < K; k0 += BK) {
        for (int i = tid; i < BM * (BK / 4); i += 256) {
            int m = i / (BK / 4);
            int kq = i % (BK / 4);
            int gn = n0 + m;
            float4 v = (gn < N_NODES)
                ? *reinterpret_cast<const float4*>(x + (size_t)gn * K + k0 + kq * 4)
                : make_float4(0.f, 0.f, 0.f, 0.f);
            xs[kq * 4 + 0][m] = v.x; xs[kq * 4 + 1][m] = v.y;
            xs[kq * 4 + 2][m] = v.z; xs[kq * 4 + 3][m] = v.w;
        }
        for (int i = tid; i < BK * (BN / 4); i += 256) {
            int kk = i / (BN / 4);
            int fq = i % (BN / 4);
            *reinterpret_cast<float4*>(&ws[kk][fq * 4]) =
                *reinterpret_cast<const float4*>(W + (size_t)(k0 + kk) * F + bn0 + fq * 4);
        }
        __syncthreads();
#pragma unroll 4
        for (int kk = 0; kk < BK; ++kk) {
            float a[TM], b[TN];
#pragma unroll
            for (int i = 0; i < TM; ++i) a[i] = xs[kk][ty * TM + i];
#pragma unroll
            for (int j = 0; j < TN; ++j) b[j] = ws[kk][tx * TN + j];
#pragma unroll
            for (int i = 0; i < TM; ++i)
#pragma unroll
                for (int j = 0; j < TN; ++j) acc[i][j] += a[i] * b[j];
        }
        __syncthreads();
    }
#pragma unroll
    for (int i = 0; i < TM; ++i) {
        int gn = n0 + ty * TM + i;
        if (gn >= N_NODES) break;
        __half* hp = h + (size_t)gn * F + bn0 + tx * TN;
        __half2 p0 = __floats2half2_rn(acc[i][0], acc[i][1]);
        __half2 p1 = __floats2half2_rn(acc[i][2], acc[i][3]);
        if constexpr (TN == 4) {
            uint2 u;
            u.x = *reinterpret_cast<unsigned int*>(&p0);
            u.y = *reinterpret_cast<unsigned int*>(&p1);
            *reinterpret_cast<uint2*>(hp) = u;
        } else {
            __half2 p2 = __floats2half2_rn(acc[i][4], acc[i][5]);
            __half2 p3 = __floats2half2_rn(acc[i][6], acc[i][7]);
            uint4 u;
            u.x = *reinterpret_cast<unsigned int*>(&p0);
            u.y = *reinterpret_cast<unsigned int*>(&p1);
            u.z = *reinterpret_cast<unsigned int*>(&p2);
            u.w = *reinterpret_cast<unsigned int*>(&p3);
            *reinterpret_cast<uint4*>(hp) = u;
        }
    }
}

// ---------------- attention logits per node ----------------

template<int F, int C>
__global__ void k_al(const __half* __restrict__ h, const float* __restrict__ a_src,
                     const float* __restrict__ a_dst,
                     float* __restrict__ al_s, float* __restrict__ al_d) {
    int idx = blockIdx.x * blockDim.x + threadIdx.x;  // n*2 + hd
    if (idx >= N_NODES * 2) return;
    int n = idx >> 1, hd = idx & 1;
    const __half2* hp = reinterpret_cast<const __half2*>(h + (size_t)n * F + hd * C);
    const float* as = a_src + hd * C;
    const float* ad = a_dst + hd * C;
    float ss = 0.f, sd = 0.f;
    for (int c = 0; c < C / 2; ++c) {
        float2 v = __half22float2(hp[c]);
        ss += v.x * as[2 * c] + v.y * as[2 * c + 1];
        sd += v.x * ad[2 * c] + v.y * ad[2 * c + 1];
    }
    al_s[idx] = ss; al_d[idx] = sd;
}

// ---------------- per-dst gather: softmax-weighted sum (fp16 h) ------------
// one wave per dst; lanes split into EPI edge-slots of LPE lanes;
// each lane loads 8 halves (16B) of one edge's h row per iteration.

template<int F, int C>
__global__ void __launch_bounds__(256) k_gather(
        const int* __restrict__ rowstart, const int* __restrict__ adj,
        const __half* __restrict__ h, const float* __restrict__ al_s,
        const float* __restrict__ al_d, const float* __restrict__ bias,
        float* __restrict__ xpre) {
    constexpr int HPL = 8;             // halves per lane
    constexpr int EPI = 512 / F;       // edges per iteration: 8, 4, 2
    constexpr int LPE = F / HPL;       // lanes per edge: 8, 16, 32
    int wave = (blockIdx.x * 256 + threadIdx.x) >> 6;
    int lane = threadIdx.x & 63;
    if (wave >= N_NODES) return;
    int n = wave;
    int rs = rowstart[n], re = rowstart[n + 1];
    float2 aldv = *reinterpret_cast<const float2*>(al_d + n * 2);

    // pass 1: per-head max over incoming edges
    float m0 = -1e30f, m1 = -1e30f;
    for (int i = rs + lane; i < re; i += 64) {
        int s = adj[i];
        float2 asv = *reinterpret_cast<const float2*>(al_s + s * 2);
        float v0 = asv.x + aldv.x; v0 = v0 > 0.f ? v0 : 0.2f * v0;
        float v1 = asv.y + aldv.y; v1 = v1 > 0.f ? v1 : 0.2f * v1;
        m0 = fmaxf(m0, v0); m1 = fmaxf(m1, v1);
    }
#pragma unroll
    for (int o = 1; o < 64; o <<= 1) {
        m0 = fmaxf(m0, __shfl_xor(m0, o));
        m1 = fmaxf(m1, __shfl_xor(m1, o));
    }

    const int es = lane / LPE;          // edge slot
    const int fl = lane % LPE;          // feature-lane within edge
    const int fi = fl * HPL;            // first feature of my 8
    const int hd = (fi >= C) ? 1 : 0;
    const float mh  = hd ? m1 : m0;
    const float alh = hd ? aldv.y : aldv.x;

    float acc[HPL];
#pragma unroll
    for (int j = 0; j < HPL; ++j) acc[j] = 0.f;
    float seh = 0.f;

    for (int i = rs; i < re; i += EPI) {
        int e = i + es;
        bool valid = (e < re);
        int s = adj[valid ? e : rs];
        float als = al_s[s * 2 + hd];
        float v = als + alh; v = v > 0.f ? v : 0.2f * v;
        float ee = valid ? __expf(v - mh) : 0.f;
        seh += ee;
        const uint4 u = *reinterpret_cast<const uint4*>(h + (size_t)s * F + fi);
        __half2 q0 = *reinterpret_cast<const __half2*>(&u.x);
        __half2 q1 = *reinterpret_cast<const __half2*>(&u.y);
        __half2 q2 = *reinterpret_cast<const __half2*>(&u.z);
        __half2 q3 = *reinterpret_cast<const __half2*>(&u.w);
        float2 f0 = __half22float2(q0), f1 = __half22float2(q1);
        float2 f2 = __half22float2(q2), f3 = __half22float2(q3);
        acc[0] += ee * f0.x; acc[1] += ee * f0.y;
        acc[2] += ee * f1.x; acc[3] += ee * f1.y;
        acc[4] += ee * f2.x; acc[5] += ee * f2.y;
        acc[6] += ee * f3.x; acc[7] += ee * f3.y;
    }

    // reduce across edge slots (lanes with same fi)
#pragma unroll
    for (int o = LPE; o < 64; o <<= 1) {
        seh += __shfl_xor(seh, o);
#pragma unroll
        for (int j = 0; j < HPL; ++j) acc[j] += __shfl_xor(acc[j], o);
    }

    if (es == 0) {
        float inv = 1.f / (seh + 1e-16f);
        float* op = xpre + (size_t)n * F + fi;
        const float* bp = bias + fi;
        float4 o0 = make_float4(acc[0] * inv + bp[0], acc[1] * inv + bp[1],
                                acc[2] * inv + bp[2], acc[3] * inv + bp[3]);
        float4 o1 = make_float4(acc[4] * inv + bp[4], acc[5] * inv + bp[5],
                                acc[6] * inv + bp[6], acc[7] * inv + bp[7]);
        *reinterpret_cast<float4*>(op) = o0;
        *reinterpret_cast<float4*>(op + 4) = o1;
    }
}

// ---------------- BatchNorm stats ----------------

template<int F>
__global__ void k_bnstats(const float* __restrict__ x, float* __restrict__ bnsum,
                          float* __restrict__ bnsumsq) {
    int tid = blockIdx.x * blockDim.x + threadIdx.x;
    const int T = 256 * 256;
    int f = tid % F;
    int nstride = T / F;
    float s = 0.f, sq = 0.f;
    for (int n = tid / F; n < N_NODES; n += nstride) {
        float v = x[(size_t)n * F + f];
        s += v; sq += v * v;
    }
    atomicAdd(&bnsum[f], s);
    atomicAdd(&bnsumsq[f], sq);
}

// ---------------- BN apply + leaky-relu + pooling (sorted-batch run flush) ----

template<int F>
__global__ void k_bnapply2(const float* __restrict__ x, const float* __restrict__ bnsum,
                           const float* __restrict__ bnsumsq, const float* __restrict__ g,
                           const float* __restrict__ be, const int* __restrict__ batch,
                           float* __restrict__ xnext, float* __restrict__ p, int poff) {
    constexpr int NGRP = 256 / F;
    constexpr int NPB = 128;              // nodes per block
    int f = threadIdx.x % F;
    int grp = threadIdx.x / F;
    int n0 = blockIdx.x * NPB;
    int nend = n0 + NPB; if (nend > N_NODES) nend = N_NODES;
    const float invN = 1.f / (float)N_NODES;
    float mean = bnsum[f] * invN;
    float var  = bnsumsq[f] * invN - mean * mean;
    float sc = rsqrtf(var + 1e-5f) * g[f];
    float bb = be[f] - mean * sc;
    int n = n0 + grp;
    if (n >= nend) return;
    float ps = 0.f;
    int cg = batch[n];
    for (; n < nend; n += NGRP) {
        float y = x[(size_t)n * F + f] * sc + bb;
        y = y > 0.f ? y : 0.01f * y;
        xnext[(size_t)n * F + f] = y;
        int bg = batch[n];
        if (bg != cg) { atomicAdd(&p[cg * POOL_F + poff + f], ps); ps = 0.f; cg = bg; }
        ps += y;
    }
    atomicAdd(&p[cg * POOL_F + poff + f], ps);
}

// ---------------- final MLP ----------------

__global__ void k_mlp(const float* __restrict__ p, const float* __restrict__ Wc1,
                      const float* __restrict__ bc1, const float* __restrict__ Wc2,
                      const float* __restrict__ bc2, const float* __restrict__ Wc3,
                      const float* __restrict__ bc3, float* __restrict__ out) {
    __shared__ float pr[POOL_F];
    __shared__ float h1[128];
    __shared__ float h2[64];
    int g = blockIdx.x, tid = threadIdx.x;
    for (int i = tid; i < POOL_F; i += 128) pr[i] = p[g * POOL_F + i];
    __syncthreads();
    float a = bc1[tid];
    for (int k = 0; k < POOL_F; ++k) a += pr[k] * Wc1[k * 128 + tid];
    a = a > 0.f ? a : 0.01f * a;
    h1[tid] = a;
    __syncthreads();
    if (tid < 64) {
        float b = bc2[tid];
        for (int k = 0; k < 128; ++k) b += h1[k] * Wc2[k * 64 + tid];
        b = b > 0.f ? b : 0.01f * b;
        h2[tid] = b;
    }
    __syncthreads();
    if (tid < 2) {
        float c = bc3[tid];
        for (int k = 0; k < 64; ++k) c += h2[k] * Wc3[k * 2 + tid];
        out[g * 2 + tid] = c;
    }
}

// ---------------- launch ----------------

extern "C" void kernel_launch(void* const* d_in, const int* in_sizes, int n_in,
                              void* d_out, int out_size, void* d_ws, size_t ws_size,
                              hipStream_t stream) {
    const float* x    = (const float*)d_in[0];
    const int*   ei   = (const int*)d_in[1];
    const int*   batch= (const int*)d_in[3];
    const float* W1  = (const float*)d_in[4];
    const float* as1 = (const float*)d_in[5];
    const float* ad1 = (const float*)d_in[6];
    const float* b1  = (const float*)d_in[7];
    const float* g1  = (const float*)d_in[8];
    const float* be1 = (const float*)d_in[9];
    const float* W2  = (const float*)d_in[10];
    const float* as2 = (const float*)d_in[11];
    const float* ad2 = (const float*)d_in[12];
    const float* b2  = (const float*)d_in[13];
    const float* g2  = (const float*)d_in[14];
    const float* be2 = (const float*)d_in[15];
    const float* W3  = (const float*)d_in[16];
    const float* as3 = (const float*)d_in[17];
    const float* ad3 = (const float*)d_in[18];
    const float* b3  = (const float*)d_in[19];
    const float* g3  = (const float*)d_in[20];
    const float* be3 = (const float*)d_in[21];
    const float* Wc1 = (const float*)d_in[22];
    const float* bc1 = (const float*)d_in[23];
    const float* Wc2 = (const float*)d_in[24];
    const float* bc2 = (const float*)d_in[25];
    const float* Wc3 = (const float*)d_in[26];
    const float* bc3 = (const float*)d_in[27];
    float* out = (float*)d_out;

    char* wsb = (char*)d_ws;
    size_t off = 0;
    auto alloc = [&](size_t b) -> void* {
        void* pp = wsb + off;
        off += (b + 255) & ~(size_t)255;
        return pp;
    };
    int*    adj      = (int*)alloc((size_t)E_TOT * 4);
    int*    rowstart = (int*)alloc((size_t)(N_NODES + 1) * 4);
    int*    deg      = (int*)alloc((size_t)N_NODES * 4);
    int*    cursor   = (int*)alloc((size_t)N_NODES * 4);
    float*  al_s     = (float*)alloc((size_t)N_NODES * 2 * 4);
    float*  al_d     = (float*)alloc((size_t)N_NODES * 2 * 4);
    float*  bn       = (float*)alloc(512 * 4);
    float*  p        = (float*)alloc((size_t)NGRAPH * POOL_F * 4);
    __half* hbuf     = (__half*)alloc((size_t)N_NODES * 256 * 2);
    float*  bufB     = (float*)alloc((size_t)N_NODES * 256 * 4);
    float*  bufC     = (float*)alloc((size_t)N_NODES * 256 * 4);

    hipMemsetAsync(deg, 0, (size_t)N_NODES * 4, stream);
    hipMemsetAsync(cursor, 0, (size_t)N_NODES * 4, stream);
    hipMemsetAsync(p, 0, (size_t)NGRAPH * POOL_F * 4, stream);

    int eb = (E_TOT + 255) / 256;
    k_deg<<<eb, 256, 0, stream>>>(ei + E_RAW_N, deg);
    k_scan<<<1, 1024, 0, stream>>>(deg, rowstart);
    k_fill<<<eb, 256, 0, stream>>>(ei, rowstart, cursor, adj);

    int gb = (N_NODES + 63) / 64;        // gemm blocks (x dim)
    int ab = (N_NODES * 2 + 255) / 256;  // al blocks
    int wb = (N_NODES + 3) / 4;          // gather blocks (4 waves each)
    int bb = (N_NODES + 127) / 128;      // bnapply blocks

    // ---- layer 1: K=128, F=64, C=32 ----
    k_gemm2<128, 64, 64><<<dim3(gb, 1), 256, 0, stream>>>(x, W1, hbuf);
    k_al<64, 32><<<ab, 256, 0, stream>>>(hbuf, as1, ad1, al_s, al_d);
    k_gather<64, 32><<<wb, 256, 0, stream>>>(rowstart, adj, hbuf, al_s, al_d, b1, bufB);
    hipMemsetAsync(bn, 0, 512 * 4, stream);
    k_bnstats<64><<<256, 256, 0, stream>>>(bufB, bn, bn + 256);
    k_bnapply2<64><<<bb, 256, 0, stream>>>(bufB, bn, bn + 256, g1, be1, batch, bufC, p, 0);

    // ---- layer 2: K=64, F=128, C=64 ----
    k_gemm2<64, 128, 128><<<dim3(gb, 1), 256, 0, stream>>>(bufC, W2, hbuf);
    k_al<128, 64><<<ab, 256, 0, stream>>>(hbuf, as2, ad2, al_s, al_d);
    k_gather<128, 64><<<wb, 256, 0, stream>>>(rowstart, adj, hbuf, al_s, al_d, b2, bufB);
    hipMemsetAsync(bn, 0, 512 * 4, stream);
    k_bnstats<128><<<256, 256, 0, stream>>>(bufB, bn, bn + 256);
    k_bnapply2<128><<<bb, 256, 0, stream>>>(bufB, bn, bn + 256, g2, be2, batch, bufC, p, 64);

    // ---- layer 3: K=128, F=256, C=128 ----
    k_gemm2<128, 256, 128><<<dim3(gb, 2), 256, 0, stream>>>(bufC, W3, hbuf);
    k_al<256, 128><<<ab, 256, 0, stream>>>(hbuf, as3, ad3, al_s, al_d);
    k_gather<256, 128><<<wb, 256, 0, stream>>>(rowstart, adj, hbuf, al_s, al_d, b3, bufB);
    hipMemsetAsync(bn, 0, 512 * 4, stream);
    k_bnstats<256><<<256, 256, 0, stream>>>(bufB, bn, bn + 256);
    k_bnapply2<256><<<bb, 256, 0, stream>>>(bufB, bn, bn + 256, g3, be3, batch, bufC, p, 192);

    // ---- readout MLP ----
    k_mlp<<<NGRAPH, 128, 0, stream>>>(p, Wc1, bc1, Wc2, bc2, Wc3, bc3, out);
}